// Round 9
// baseline (33.240 us; speedup 1.0000x reference)
//
#include <hip/hip_runtime.h>
#include <math.h>

// out[c*65536 + pix] = in[(rho(pix)*256 + th(pix))*512 + c] * WSUM
// in : (1,256,256,512) f32 NHWC-flat ; out: warped-(C,H,W) flat f32.
// v9: 32ch x 512px (2-row) tiles — each channel's output run is 2KB
// contiguous (vs 1KB), improving write page locality; adjacent-row arc
// reuse becomes intra-block. Same XCD row-band swizzle (XCD k owns rows
// [32k,32k+32)), same conflict-free XOR LDS transpose, same nt stores.
// 66KB LDS -> 2 blocks/CU.

typedef float v4f __attribute__((ext_vector_type(4)));

__global__ __launch_bounds__(256) void InverseLogPolar_kernel(
        const float* __restrict__ in, float* __restrict__ out) {
    __shared__ int   sBase[512];
    __shared__ float tile[32 * 512];   // [ch_row r][px p], col physical = p ^ (((r>>2)&7)<<2)

    const int b    = blockIdx.x;
    const int rp   = ((b & 7) << 4) | ((b >> 3) & 15);  // row-pair; XCD k owns rows [32k,32k+32)
    const int ct   = b >> 7;                            // channel tile 0..15
    const int t    = threadIdx.x;
    const int pix0 = rp << 9;                           // 512 pixels per block (2 rows)
    const int c0   = ct << 5;                           // 32 channels per block

    // ---- inverse log-polar index, float64, mirrors numpy op-for-op ----
    #pragma unroll
    for (int h = 0; h < 2; ++h) {
        const int i = (rp << 1) + h;
        const int j = t;
        const double dy = (double)i - 127.5;
        const double dx = (double)j - 127.5;
        const double r  = sqrt(dx * dx + dy * dy);
        const double rmax  = sqrt(127.5 * 127.5 + 127.5 * 127.5);
        const double lrmax = log(rmax);
        double rho   = (r > 0.5) ? (log(fmax(r, 1e-6)) / lrmax) * 255.0 : 0.0;
        double theta = ((atan2(dy, dx) + M_PI) / (2.0 * M_PI)) * 255.0;
        double rr = fmin(fmax(rint(rho),   0.0), 255.0);
        double tt = fmin(fmax(rint(theta), 0.0), 255.0);
        sBase[(h << 8) + t] = ((int)rr << 17) | ((int)tt << 9);   // (rho*256+th)*512
    }
    __syncthreads();

    const float WSUM = (float)(0.2989 + 0.587 + 0.114);

    // ---- phase 1: gather global -> registers ----
    // chunk k (0..4095): pixel p = k>>3, channel float4 cj = (k&7)*4.
    // 8 lanes per pixel => 128B contiguous run per gathered cell slice.
    float4 v[16];
    #pragma unroll
    for (int it = 0; it < 16; ++it) {
        const int k = (it << 8) + t;
        const int p = k >> 3;
        const int cj = (k & 7) << 2;
        v[it] = *reinterpret_cast<const float4*>(in + sBase[p] + c0 + cj);
    }
    // ---- registers -> LDS transpose (swizzled; 2-way bank = free) ----
    #pragma unroll
    for (int it = 0; it < 16; ++it) {
        const int k = (it << 8) + t;
        const int p = k >> 3;
        const int cj = (k & 7) << 2;
        const int pp = p ^ ((k & 7) << 2);   // s(r) = ((r>>2)&7)<<2, r = cj+d
        float* r0 = &tile[cj * 512 + pp];
        r0[0]    = v[it].x * WSUM;
        r0[512]  = v[it].y * WSUM;
        r0[1024] = v[it].z * WSUM;
        r0[1536] = v[it].w * WSUM;
    }
    __syncthreads();

    // ---- phase 2: LDS -> global; per channel 2KB contiguous nt stores ----
    const int l = t & 63;
    const int w = t >> 6;
    #pragma unroll
    for (int it2 = 0; it2 < 16; ++it2) {
        const int c    = (w << 3) + (it2 >> 1);   // wave-uniform channel row
        const int half = it2 & 1;                 // halves consecutive -> 2KB run per c
        const int s    = ((c >> 2) & 7) << 2;
        const v4f o = *reinterpret_cast<const v4f*>(
            &tile[c * 512 + (half << 8) + ((l << 2) ^ s)]);
        __builtin_nontemporal_store(
            o, reinterpret_cast<v4f*>(out + ((size_t)(c0 + c) << 16) + pix0
                                          + (half << 8) + (l << 2)));
    }
}

extern "C" void kernel_launch(void* const* d_in, const int* in_sizes, int n_in,
                              void* d_out, int out_size, void* d_ws, size_t ws_size,
                              hipStream_t stream) {
    const float* in = (const float*)d_in[0];
    float* out = (float*)d_out;
    dim3 grid(2048);    // 128 row-pairs x 16 channel tiles, XCD row-band swizzled
    dim3 block(256);
    hipLaunchKernelGGL(InverseLogPolar_kernel, grid, block, 0, stream, in, out);
}

// Round 10
// 32.787 us; speedup vs baseline: 1.0138x; 1.0138x over previous
//
#include <hip/hip_runtime.h>
#include <math.h>

// out[c*65536 + pix] = in[(rho(pix)*256 + th(pix))*512 + c] * WSUM
// in : (1,256,256,512) f32 NHWC-flat ; out: warped-(C,H,W) flat f32.
// v10 == v6 (best measured, 32.49us): 64-ch x 256-px tiles + XOR-swizzled
// LDS transpose + XCD row-band swizzle + nt coalesced stores.
// Roofline accounting: 134MB write + ~50MB reuse-reduced fetch in 32.5us
// = 5.7 TB/s effective, ~90% of the 6.29 TB/s copy ceiling; bank-conflict,
// burst-length, dedup-partition, and TLP levers all measured null/negative.

typedef float v4f __attribute__((ext_vector_type(4)));

__global__ __launch_bounds__(256) void InverseLogPolar_kernel(
        const float* __restrict__ in, float* __restrict__ out) {
    __shared__ int   sBase[256];
    __shared__ float tile[64 * 256];   // [ch_row r][px p], addr = r*256 + (p ^ (((r>>2)&7)<<2))

    const int b    = blockIdx.x;
    const int row  = ((b & 7) << 5) | ((b >> 3) & 31);  // XCD k owns rows [32k, 32k+32)
    const int ct   = b >> 8;                            // channel tile 0..7
    const int t    = threadIdx.x;
    const int pix0 = row << 8;
    const int c0   = ct << 6;                           // 64 channels per block

    // ---- inverse log-polar index, float64, mirrors numpy op-for-op ----
    {
        const double dy = (double)row - 127.5;
        const double dx = (double)t   - 127.5;
        const double r  = sqrt(dx * dx + dy * dy);
        const double rmax  = sqrt(127.5 * 127.5 + 127.5 * 127.5);
        const double lrmax = log(rmax);
        double rho   = (r > 0.5) ? (log(fmax(r, 1e-6)) / lrmax) * 255.0 : 0.0;
        double theta = ((atan2(dy, dx) + M_PI) / (2.0 * M_PI)) * 255.0;
        double rr = fmin(fmax(rint(rho),   0.0), 255.0);
        double tt = fmin(fmax(rint(theta), 0.0), 255.0);
        sBase[t] = ((int)rr << 17) | ((int)tt << 9);   // (rho*256 + th) * 512
    }
    __syncthreads();

    const float WSUM = (float)(0.2989 + 0.587 + 0.114);

    // ---- phase 1: gather global -> registers ----
    // chunk k: pixel p = k>>4, channel offset cj = (k&15)*4.
    // 16 lanes per pixel => 256B contiguous run per gathered cell slice.
    float4 v[16];
    #pragma unroll
    for (int it = 0; it < 16; ++it) {
        const int k = (it << 8) + t;
        const int p = k >> 4;
        const int cj = (k & 15) << 2;
        v[it] = *reinterpret_cast<const float4*>(in + sBase[p] + c0 + cj);
    }
    // ---- registers -> LDS transpose (swizzled; 2-way bank = free) ----
    #pragma unroll
    for (int it = 0; it < 16; ++it) {
        const int k = (it << 8) + t;
        const int p = k >> 4;
        const int cj = (k & 15) << 2;
        const int pp = p ^ ((k & 7) << 2);   // ((r>>2)&7)<<2 with r=cj+d, d<4
        float* r0 = &tile[cj * 256 + pp];
        r0[0]       = v[it].x * WSUM;
        r0[256]     = v[it].y * WSUM;
        r0[512]     = v[it].z * WSUM;
        r0[768]     = v[it].w * WSUM;
    }
    __syncthreads();

    // ---- phase 2: LDS -> global, conflict-free b128, 1KB coalesced nt stores ----
    const int l = t & 63;
    const int w = t >> 6;
    #pragma unroll
    for (int it2 = 0; it2 < 16; ++it2) {
        const int c = (w << 4) + it2;                       // wave-uniform channel row
        const int pl = (l ^ ((c >> 2) & 7)) << 2;           // swizzled physical pixel group
        const v4f o = *reinterpret_cast<const v4f*>(&tile[c * 256 + pl]);
        __builtin_nontemporal_store(
            o, reinterpret_cast<v4f*>(out + ((size_t)(c0 + c) << 16) + pix0 + (pl ^ ((((c >> 2) & 7) << 2)))));
    }
}

extern "C" void kernel_launch(void* const* d_in, const int* in_sizes, int n_in,
                              void* d_out, int out_size, void* d_ws, size_t ws_size,
                              hipStream_t stream) {
    const float* in = (const float*)d_in[0];
    float* out = (float*)d_out;
    dim3 grid(2048);    // 256 rows x 8 channel tiles, XCD row-band swizzled
    dim3 block(256);
    hipLaunchKernelGGL(InverseLogPolar_kernel, grid, block, 0, stream, in, out);
}